// Round 14
// baseline (307.081 us; speedup 1.0000x reference)
//
#include <hip/hip_runtime.h>
#include <hip/hip_bf16.h>
#include <math.h>

#define B_SZ 4
#define C_SZ 512
#define N_SZ 4096
#define D_SZ 64
#define SHIFT 60.0f

typedef __attribute__((ext_vector_type(4))) float f32x4;
typedef __attribute__((ext_vector_type(8))) short bf16x8;
typedef __attribute__((ext_vector_type(8))) _Float16 f16x8;

// fp32 -> bf16 RNE via native convert
__device__ __forceinline__ short f2bf(float x) {
    return (short)__bfloat16_as_ushort(__float2bfloat16(x));
}

__device__ __forceinline__ bf16x8 pack8(float4 a, float4 b) {
    bf16x8 r;
    r[0] = f2bf(a.x); r[1] = f2bf(a.y); r[2] = f2bf(a.z); r[3] = f2bf(a.w);
    r[4] = f2bf(b.x); r[5] = f2bf(b.y); r[6] = f2bf(b.z); r[7] = f2bf(b.w);
    return r;
}

// fp32x8 -> fp16x8 (RNE)
__device__ __forceinline__ f16x8 pack8h(float4 a, float4 b) {
    f16x8 r;
    r[0] = (_Float16)a.x; r[1] = (_Float16)a.y; r[2] = (_Float16)a.z; r[3] = (_Float16)a.w;
    r[4] = (_Float16)b.x; r[5] = (_Float16)b.y; r[6] = (_Float16)b.z; r[7] = (_Float16)b.w;
    return r;
}

// ---------------------------------------------------------------------------
// Pre-pass: a fp32 -> bf16 (PV operand)
// ---------------------------------------------------------------------------
__global__ __launch_bounds__(256) void conv_a_kernel(
    const float* __restrict__ amat, short* __restrict__ abf)
{
    size_t i = ((size_t)blockIdx.x * 256 + threadIdx.x) * 8;
    float4 a0 = ((const float4*)(amat + i))[0];
    float4 a1 = ((const float4*)(amat + i))[1];
    *(bf16x8*)(abf + i) = pack8(a0, a1);
}

// Pre-pass: c fp32 -> fp16 (QK operand)
__global__ __launch_bounds__(256) void conv_c_kernel(
    const float* __restrict__ cmat, _Float16* __restrict__ ch)
{
    size_t i = ((size_t)blockIdx.x * 256 + threadIdx.x) * 8;
    float4 c0 = ((const float4*)(cmat + i))[0];
    float4 c1 = ((const float4*)(cmat + i))[1];
    *(f16x8*)(ch + i) = pack8h(c0, c1);
}

// ---------------------------------------------------------------------------
// Fused pass (pv8): R11 structure at HALF the m-tile -> 4 blocks/CU.
// Tile 256ch x 32m, 4 waves; grid 1024 = 4 blocks/CU (launch_bounds(256,4)),
// 16 waves/CU. Independent blocks' barriers interleave -> latency hidden by
// TLP (R13 showed reg-prefetch ILP can't fit the VGPR budget).
// fp16 QK (2 MFMA/tile), bf16 P in LDS (4 buffers), shift-softmax, per-lane
// L sums. No reg prefetch: af/K loaded where used, ~115 VGPR.
// ---------------------------------------------------------------------------
__global__ __launch_bounds__(256, 4) void pv8_kernel(
    const float* __restrict__ amat, const float* __restrict__ bmat,
    const short* __restrict__ abf, const _Float16* __restrict__ chm,
    float* __restrict__ out)
{
    const int t = threadIdx.x;
    const int lane = t & 63;
    const int l15 = lane & 15;
    const int lg = lane >> 4;
    const int w = t >> 6;

    const int bid = blockIdx.x;
    const int slice = bid & 7;         // -> XCD via dispatch round-robin
    const int gm0 = (bid >> 3) * 32;   // m-tile (32 rows)
    const int gc0 = (slice & 1) * 256; // ch half
    const int bz = slice >> 1;         // batch

    __shared__ __align__(16) short smp[4][32 * 72];  // P [m][n], 4 buffers
    __shared__ float ldsL4[4][32];

    // Q fragments (fp32 -> fp16 in regs, once per block)
    f16x8 qf[2][2];
#pragma unroll
    for (int mf = 0; mf < 2; ++mf)
#pragma unroll
        for (int kf = 0; kf < 2; ++kf) {
            const float* qp = bmat + ((size_t)bz * N_SZ + gm0 + mf * 16 + l15) * D_SZ
                              + kf * 32 + lg * 8;
            float4 q0 = ((const float4*)qp)[0];
            float4 q1 = ((const float4*)qp)[1];
            qf[mf][kf] = pack8h(q0, q1);
        }

    f32x4 acc[4][2];
#pragma unroll
    for (int i = 0; i < 4; ++i)
#pragma unroll
        for (int j = 0; j < 2; ++j)
            acc[i][j] = (f32x4){0.f, 0.f, 0.f, 0.f};

    float psum[2][4];
#pragma unroll
    for (int i = 0; i < 2; ++i)
#pragma unroll
        for (int j = 0; j < 4; ++j) psum[i][j] = 0.0f;

    // K-fragment base: c row (w*16 + l15), d-octet lg*8
    const _Float16* kb = chm + ((size_t)bz * N_SZ + w * 16 + l15) * D_SZ + lg * 8;
    // A-fragment base: a row (gc0 + w*64 + l15), n-octet lg*8
    const short* ab = abf + ((size_t)bz * C_SZ + gc0 + w * 64 + l15) * N_SZ + lg * 8;

    // QK for chunk n0 -> P into smp[pbuf]; per-lane row sums
    auto QK = [&](int n0, int pbuf) {
        const _Float16* kp = kb + (size_t)n0 * D_SZ;
        f16x8 k0 = *(const f16x8*)(kp);
        f16x8 k1 = *(const f16x8*)(kp + 32);
#pragma unroll
        for (int mf = 0; mf < 2; ++mf) {
            f32x4 s = {0.f, 0.f, 0.f, 0.f};
            s = __builtin_amdgcn_mfma_f32_16x16x32_f16(qf[mf][0], k0, s, 0, 0, 0);
            s = __builtin_amdgcn_mfma_f32_16x16x32_f16(qf[mf][1], k1, s, 0, 0, 0);
#pragma unroll
            for (int r = 0; r < 4; ++r) {
                float p = __expf(s[r] - SHIFT);
                psum[mf][r] += p;
                smp[pbuf][(mf * 16 + lg * 4 + r) * 72 + w * 16 + l15] = f2bf(p);
            }
        }
    };

    // PV for chunk n0 reading smp[pbuf]
    auto PV = [&](int n0, int pbuf) {
#pragma unroll
        for (int kf = 0; kf < 2; ++kf) {
            bf16x8 pf[2], af[4];
#pragma unroll
            for (int mf = 0; mf < 2; ++mf)
                pf[mf] = *(const bf16x8*)&smp[pbuf][(mf * 16 + l15) * 72 + kf * 32 + lg * 8];
#pragma unroll
            for (int chf = 0; chf < 4; ++chf)
                af[chf] = *(const bf16x8*)(ab + (size_t)chf * 16 * N_SZ + n0 + kf * 32);
#pragma unroll
            for (int chf = 0; chf < 4; ++chf)
#pragma unroll
                for (int mf = 0; mf < 2; ++mf)
                    acc[chf][mf] = __builtin_amdgcn_mfma_f32_16x16x32_bf16(
                        af[chf], pf[mf], acc[chf][mf], 0, 0, 0);
        }
    };

    QK(0, 0);
    QK(64, 1);
    for (int s = 0; s < 31; ++s) {
        __syncthreads();
        PV(s * 128, (2 * s) & 3);
        PV(s * 128 + 64, (2 * s + 1) & 3);
        QK((s + 1) * 128, (2 * s + 2) & 3);
        QK((s + 1) * 128 + 64, (2 * s + 3) & 3);
    }
    __syncthreads();
    PV(31 * 128, 2);
    PV(31 * 128 + 64, 3);

    // L reduction: butterfly over the 16 l15 lanes, then cross-wave via LDS.
#pragma unroll
    for (int mf = 0; mf < 2; ++mf)
#pragma unroll
        for (int r = 0; r < 4; ++r) {
            float v = psum[mf][r];
            v += __shfl_xor(v, 1, 64);
            v += __shfl_xor(v, 2, 64);
            v += __shfl_xor(v, 4, 64);
            v += __shfl_xor(v, 8, 64);
            if (l15 == 0) ldsL4[w][mf * 16 + lg * 4 + r] = v;
        }
    __syncthreads();

    float ri[2];
#pragma unroll
    for (int mf = 0; mf < 2; ++mf) {
        int m = mf * 16 + l15;
        ri[mf] = 1.0f / (ldsL4[0][m] + ldsL4[1][m] + ldsL4[2][m] + ldsL4[3][m]);
    }

    // epilogue: out = acc / L + a
#pragma unroll
    for (int chf = 0; chf < 4; ++chf)
#pragma unroll
        for (int mf = 0; mf < 2; ++mf) {
            const int m = gm0 + mf * 16 + l15;
#pragma unroll
            for (int r = 0; r < 4; ++r) {
                const int ch = gc0 + w * 64 + chf * 16 + lg * 4 + r;
                size_t o = ((size_t)bz * C_SZ + ch) * N_SZ + m;
                out[o] = acc[chf][mf][r] * ri[mf] + amat[o];
            }
        }
}

extern "C" void kernel_launch(void* const* d_in, const int* in_sizes, int n_in,
                              void* d_out, int out_size, void* d_ws, size_t ws_size,
                              hipStream_t stream) {
    const float* a = (const float*)d_in[0];
    const float* b = (const float*)d_in[1];
    const float* c = (const float*)d_in[2];
    float* out = (float*)d_out;

    // ws layout: abf (bf16, 8 MB) | c fp16 (2 MB)
    const size_t abf_b = (size_t)B_SZ * C_SZ * N_SZ * 2;

    short* abf = (short*)d_ws;
    _Float16* chm = (_Float16*)((char*)d_ws + abf_b);

    conv_a_kernel<<<dim3((B_SZ * C_SZ * N_SZ) / (256 * 8)), 256, 0, stream>>>(a, abf);
    conv_c_kernel<<<dim3((B_SZ * N_SZ * D_SZ) / (256 * 8)), 256, 0, stream>>>(c, chm);
    pv8_kernel<<<dim3(1024), 256, 0, stream>>>(a, b, abf, chm, out);
}

// Round 15
// 177.104 us; speedup vs baseline: 1.7339x; 1.7339x over previous
//
#include <hip/hip_runtime.h>
#include <hip/hip_bf16.h>
#include <math.h>

#define B_SZ 4
#define C_SZ 512
#define N_SZ 4096
#define D_SZ 64
#define SHIFT 60.0f

typedef __attribute__((ext_vector_type(4))) float f32x4;
typedef __attribute__((ext_vector_type(8))) short bf16x8;
typedef __attribute__((ext_vector_type(4))) short s16x4;
typedef __attribute__((ext_vector_type(8))) _Float16 f16x8;

// fp32 -> bf16 RNE via native convert
__device__ __forceinline__ short f2bf(float x) {
    return (short)__bfloat16_as_ushort(__float2bfloat16(x));
}

__device__ __forceinline__ bf16x8 pack8(float4 a, float4 b) {
    bf16x8 r;
    r[0] = f2bf(a.x); r[1] = f2bf(a.y); r[2] = f2bf(a.z); r[3] = f2bf(a.w);
    r[4] = f2bf(b.x); r[5] = f2bf(b.y); r[6] = f2bf(b.z); r[7] = f2bf(b.w);
    return r;
}

// fp32x8 -> fp16x8 (RNE)
__device__ __forceinline__ f16x8 pack8h(float4 a, float4 b) {
    f16x8 r;
    r[0] = (_Float16)a.x; r[1] = (_Float16)a.y; r[2] = (_Float16)a.z; r[3] = (_Float16)a.w;
    r[4] = (_Float16)b.x; r[5] = (_Float16)b.y; r[6] = (_Float16)b.z; r[7] = (_Float16)b.w;
    return r;
}

// ---------------------------------------------------------------------------
// Pre-pass: a fp32 -> bf16 (PV operand)
// ---------------------------------------------------------------------------
__global__ __launch_bounds__(256) void conv_a_kernel(
    const float* __restrict__ amat, short* __restrict__ abf)
{
    size_t i = ((size_t)blockIdx.x * 256 + threadIdx.x) * 8;
    float4 a0 = ((const float4*)(amat + i))[0];
    float4 a1 = ((const float4*)(amat + i))[1];
    *(bf16x8*)(abf + i) = pack8(a0, a1);
}

// Pre-pass: c fp32 -> fp16 (QK operand)
__global__ __launch_bounds__(256) void conv_c_kernel(
    const float* __restrict__ cmat, _Float16* __restrict__ ch)
{
    size_t i = ((size_t)blockIdx.x * 256 + threadIdx.x) * 8;
    float4 c0 = ((const float4*)(cmat + i))[0];
    float4 c1 = ((const float4*)(cmat + i))[1];
    *(f16x8*)(ch + i) = pack8h(c0, c1);
}

// ---------------------------------------------------------------------------
// Fused pass (pv9): R11 structure + SWAPPED QK.
//   mfma(A=K, B=Q) -> C[n][m]: lane l15 = m, reg r = consecutive n.
//   - P-store: one ds_write_b64 (short4, 4 consecutive n) per mf
//     (was 4 scattered ds_write_b16) -> LDS write issue /4.
//   - L-reduce: 2 shuffles (lg groups) instead of 4.
//   Q/K register fragments identical to R11 (A/B layouts share l15/lg
//   keying); PV unchanged. Load-at-use (R13 prefetch was neutral).
// ---------------------------------------------------------------------------
__global__ __launch_bounds__(256, 2) void pv9_kernel(
    const float* __restrict__ amat, const float* __restrict__ bmat,
    const short* __restrict__ abf, const _Float16* __restrict__ chm,
    float* __restrict__ out)
{
    const int t = threadIdx.x;
    const int lane = t & 63;
    const int l15 = lane & 15;
    const int lg = lane >> 4;
    const int w = t >> 6;

    const int bid = blockIdx.x;
    const int slice = bid & 7;         // -> XCD via dispatch round-robin
    const int gm0 = (bid >> 3) * 64;   // m-tile
    const int gc0 = (slice & 1) * 256; // ch half
    const int bz = slice >> 1;         // batch

    __shared__ __align__(16) short smp[4][64 * 72];  // P [m][n], 4 buffers
    __shared__ float ldsL4[4][64];

    // Q fragments (fp32 -> fp16 in regs, once per block); used as MFMA B.
    f16x8 qf[4][2];
#pragma unroll
    for (int mf = 0; mf < 4; ++mf)
#pragma unroll
        for (int kf = 0; kf < 2; ++kf) {
            const float* qp = bmat + ((size_t)bz * N_SZ + gm0 + mf * 16 + l15) * D_SZ
                              + kf * 32 + lg * 8;
            float4 q0 = ((const float4*)qp)[0];
            float4 q1 = ((const float4*)qp)[1];
            qf[mf][kf] = pack8h(q0, q1);
        }

    f32x4 acc[4][4];
#pragma unroll
    for (int i = 0; i < 4; ++i)
#pragma unroll
        for (int j = 0; j < 4; ++j)
            acc[i][j] = (f32x4){0.f, 0.f, 0.f, 0.f};

    // psum[mf]: partial row-sum for m = mf*16 + l15 (this lane's 4 n + chunks)
    float psum[4] = {0.f, 0.f, 0.f, 0.f};

    // K-fragment base (MFMA A): c row (w*16 + l15), d-octet lg*8
    const _Float16* kb = chm + ((size_t)bz * N_SZ + w * 16 + l15) * D_SZ + lg * 8;
    // A-fragment base (PV A): a row (gc0 + w*64 + l15), n-octet lg*8
    const short* ab = abf + ((size_t)bz * C_SZ + gc0 + w * 64 + l15) * N_SZ + lg * 8;

    // QK for chunk n0 -> P into smp[pbuf] (swapped: C[n][m])
    auto QK = [&](int n0, int pbuf) {
        const _Float16* kp = kb + (size_t)n0 * D_SZ;
        f16x8 k0 = *(const f16x8*)(kp);
        f16x8 k1 = *(const f16x8*)(kp + 32);
#pragma unroll
        for (int mf = 0; mf < 4; ++mf) {
            f32x4 s = {0.f, 0.f, 0.f, 0.f};
            s = __builtin_amdgcn_mfma_f32_16x16x32_f16(k0, qf[mf][0], s, 0, 0, 0);
            s = __builtin_amdgcn_mfma_f32_16x16x32_f16(k1, qf[mf][1], s, 0, 0, 0);
            // lane holds P[n = w*16 + lg*4 + r][m = mf*16 + l15], r = 0..3
            s16x4 pw;
            float p0 = __expf(s[0] - SHIFT);
            float p1 = __expf(s[1] - SHIFT);
            float p2 = __expf(s[2] - SHIFT);
            float p3 = __expf(s[3] - SHIFT);
            psum[mf] += (p0 + p1) + (p2 + p3);
            pw[0] = f2bf(p0); pw[1] = f2bf(p1); pw[2] = f2bf(p2); pw[3] = f2bf(p3);
            // P[m][n] layout: addr = m*72 + n; 4 consecutive n -> one b64
            *(s16x4*)&smp[pbuf][(mf * 16 + l15) * 72 + w * 16 + lg * 4] = pw;
        }
    };

    // PV for chunk n0 reading smp[pbuf] (unchanged)
    auto PV = [&](int n0, int pbuf) {
#pragma unroll
        for (int kf = 0; kf < 2; ++kf) {
            bf16x8 pf[4], af[4];
#pragma unroll
            for (int mf = 0; mf < 4; ++mf)
                pf[mf] = *(const bf16x8*)&smp[pbuf][(mf * 16 + l15) * 72 + kf * 32 + lg * 8];
#pragma unroll
            for (int chf = 0; chf < 4; ++chf)
                af[chf] = *(const bf16x8*)(ab + (size_t)chf * 16 * N_SZ + n0 + kf * 32);
#pragma unroll
            for (int chf = 0; chf < 4; ++chf)
#pragma unroll
                for (int mf = 0; mf < 4; ++mf)
                    acc[chf][mf] = __builtin_amdgcn_mfma_f32_16x16x32_bf16(
                        af[chf], pf[mf], acc[chf][mf], 0, 0, 0);
        }
    };

    QK(0, 0);
    QK(64, 1);
    for (int s = 0; s < 31; ++s) {
        __syncthreads();
        PV(s * 128, (2 * s) & 3);
        PV(s * 128 + 64, (2 * s + 1) & 3);
        QK((s + 1) * 128, (2 * s + 2) & 3);
        QK((s + 1) * 128 + 64, (2 * s + 3) & 3);
    }
    __syncthreads();
    PV(31 * 128, 2);
    PV(31 * 128 + 64, 3);

    // L reduction: sum over lg groups (xor 16, 32), then cross-wave via LDS.
#pragma unroll
    for (int mf = 0; mf < 4; ++mf) {
        float v = psum[mf];
        v += __shfl_xor(v, 16, 64);
        v += __shfl_xor(v, 32, 64);
        if (lg == 0) ldsL4[w][mf * 16 + l15] = v;
    }
    __syncthreads();

    float ri[4];
#pragma unroll
    for (int mf = 0; mf < 4; ++mf) {
        int m = mf * 16 + l15;
        ri[mf] = 1.0f / (ldsL4[0][m] + ldsL4[1][m] + ldsL4[2][m] + ldsL4[3][m]);
    }

    // epilogue: out = acc / L + a
#pragma unroll
    for (int chf = 0; chf < 4; ++chf)
#pragma unroll
        for (int mf = 0; mf < 4; ++mf) {
            const int m = gm0 + mf * 16 + l15;
#pragma unroll
            for (int r = 0; r < 4; ++r) {
                const int ch = gc0 + w * 64 + chf * 16 + lg * 4 + r;
                size_t o = ((size_t)bz * C_SZ + ch) * N_SZ + m;
                out[o] = acc[chf][mf][r] * ri[mf] + amat[o];
            }
        }
}

extern "C" void kernel_launch(void* const* d_in, const int* in_sizes, int n_in,
                              void* d_out, int out_size, void* d_ws, size_t ws_size,
                              hipStream_t stream) {
    const float* a = (const float*)d_in[0];
    const float* b = (const float*)d_in[1];
    const float* c = (const float*)d_in[2];
    float* out = (float*)d_out;

    // ws layout: abf (bf16, 8 MB) | c fp16 (2 MB)
    const size_t abf_b = (size_t)B_SZ * C_SZ * N_SZ * 2;

    short* abf = (short*)d_ws;
    _Float16* chm = (_Float16*)((char*)d_ws + abf_b);

    conv_a_kernel<<<dim3((B_SZ * C_SZ * N_SZ) / (256 * 8)), 256, 0, stream>>>(a, abf);
    conv_c_kernel<<<dim3((B_SZ * N_SZ * D_SZ) / (256 * 8)), 256, 0, stream>>>(c, chm);
    pv9_kernel<<<dim3(512), 256, 0, stream>>>(a, b, abf, chm, out);
}